// Round 4
// baseline (1130.714 us; speedup 1.0000x reference)
//
#include <hip/hip_runtime.h>
#include <math.h>

#define NB 64
#define NN 4096
#define ND 256
#define NS 256
#define NK 8
#define NH 512
#define NROW (NB*NN)
#define NSLOT (NB*NK)
#define EPSA 1e-8f
#define NCG 64            // n-chunks per batch in attn (64 n each)

typedef unsigned short u16;
typedef unsigned int   u32;
typedef __bf16 bf16x8 __attribute__((ext_vector_type(8)));
typedef float  f32x4  __attribute__((ext_vector_type(4)));

__device__ __forceinline__ float bf2f(u16 u) {
  union { u32 i; float f; } v; v.i = ((u32)u) << 16; return v.f;
}
__device__ __forceinline__ u16 f2bf(float f) {
  union { float f; u32 i; } v; v.f = f;
  u32 x = v.i;
  return (u16)((x + 0x7FFFu + ((x >> 16) & 1u)) >> 16);
}
__device__ __forceinline__ u32 pack2(float a, float b) {
  return (u32)f2bf(a) | ((u32)f2bf(b) << 16);
}

// ---------------- workspace layout (bytes) ----------------
#define OFF_XBF    0ULL            // 262144*256 bf16 = 134217728
#define OFF_KG     134217728ULL    // k  [262144][256] bf16 = 134217728
#define OFF_VTG    268435456ULL    // vT [64][256][4096] bf16 = 134217728
#define OFF_SLOTS  402653184ULL    // 512*256 f32
#define OFF_QBF    403177472ULL    // 512*256 bf16
#define OFF_UPDP   403439616ULL    // 64*64*8*256 f32 = 33554432
#define OFF_SUMSP  436994048ULL    // 64*64*8 f32 = 131072
#define OFF_WC     437125120ULL    // 512*256 bf16
#define OFF_WQT    437387264ULL    // 256*256 f32
#define OFF_WIHT   437649408ULL    // 256*768 f32
#define OFF_WHHT   438435840ULL    // 256*768 f32
#define OFF_W1T    439222272ULL    // 256*512 f32
#define OFF_W2T    439746560ULL    // 512*256 f32 (end ~440 MB)

// ---------------- K0: weight prep (proven) ----------------
__global__ __launch_bounds__(256) void prep_kernel(
    const float* __restrict__ Wq, const float* __restrict__ Wk, const float* __restrict__ Wv,
    const float* __restrict__ Wih, const float* __restrict__ Whh,
    const float* __restrict__ W1, const float* __restrict__ W2,
    u16* __restrict__ Wc, float* __restrict__ WqT, float* __restrict__ WihT,
    float* __restrict__ WhhT, float* __restrict__ W1T, float* __restrict__ W2T)
{
  int idx = blockIdx.x * 256 + threadIdx.x;   // 768*256
  if (idx < 512*256) {
    int j = idx >> 8, d = idx & 255;
    float w = (j < 256) ? Wk[idx] * 0.0625f : Wv[idx - 65536];
    Wc[idx] = f2bf(w);
    W1T[d*512 + j] = W1[idx];
  }
  if (idx < 256*256) {
    int j = idx >> 8, d = idx & 255;
    WqT[d*256 + j] = Wq[idx];
  }
  if (idx < 768*256) {
    int j = idx >> 8, d = idx & 255;
    WihT[d*768 + j] = Wih[idx];
    WhhT[d*768 + j] = Whh[idx];
  }
  if (idx < 256*512) {
    int j = idx >> 9, h = idx & 511;
    W2T[h*256 + j] = W2[idx];
  }
}

// ---------------- K1: slots init ----------------
__global__ __launch_bounds__(256) void slots_init_kernel(
    const float* __restrict__ noise, const float* __restrict__ mu,
    const float* __restrict__ lsig, float* __restrict__ slots)
{
  int idx = blockIdx.x * 256 + threadIdx.x;
  int s = idx & 255;
  slots[idx] = mu[s] + expf(lsig[s]) * noise[idx];
}

// ---------------- K2: LayerNorm(inputs) -> bf16 (r1 proven) ----------------
__global__ __launch_bounds__(256) void ln_cast_kernel(
    const float* __restrict__ x, const float* __restrict__ g, const float* __restrict__ bb,
    u16* __restrict__ out)
{
  int row = blockIdx.x * 4 + (threadIdx.x >> 6);
  int lane = threadIdx.x & 63;
  float4 xv = *(const float4*)(x + (size_t)row * 256 + lane * 4);
  float s  = xv.x + xv.y + xv.z + xv.w;
  float sq = xv.x*xv.x + xv.y*xv.y + xv.z*xv.z + xv.w*xv.w;
  #pragma unroll
  for (int m = 32; m >= 1; m >>= 1) { s += __shfl_xor(s, m, 64); sq += __shfl_xor(sq, m, 64); }
  float mean = s * (1.f/256.f);
  float rstd = rsqrtf(sq * (1.f/256.f) - mean*mean + 1e-5f);
  float4 gv = *(const float4*)(g + lane*4);
  float4 bv = *(const float4*)(bb + lane*4);
  ushort4 o;
  o.x = f2bf((xv.x - mean) * rstd * gv.x + bv.x);
  o.y = f2bf((xv.y - mean) * rstd * gv.y + bv.y);
  o.z = f2bf((xv.z - mean) * rstd * gv.z + bv.z);
  o.w = f2bf((xv.w - mean) * rstd * gv.w + bv.w);
  *(ushort4*)(out + (size_t)row * 256 + lane*4) = o;
}

// ---------------- K3: kv GEMM (r1 core) + vT epilogue ----------------
// grid (2048, 4). bn 0,1 -> k cols; bn 2,3 -> v cols, LDS-transposed to vtg.
__global__ __launch_bounds__(256) void gemm_kv_kernel(
    const u16* __restrict__ A, const u16* __restrict__ Bt,
    u16* __restrict__ kg, u16* __restrict__ vtg)
{
  __shared__ u16 smem[17408];           // As[0..4095] | Bs[4096..8191] ; tr = whole (128x136)
  u16* As = smem;
  u16* Bs = smem + 4096;
  const int tid = threadIdx.x;
  const int lane = tid & 63;
  const int wv = tid >> 6;
  const int bm = blockIdx.x;
  const int bn = blockIdx.y;
  const int wm = (wv & 1) * 64;
  const int wn = (wv >> 1) * 64;

  f32x4 acc[4][4] = {};

  for (int k0 = 0; k0 < 256; k0 += 32) {
    #pragma unroll
    for (int r = 0; r < 2; ++r) {
      int off = ((r*4 + wv) << 10) + lane*16;   // byte offset into 8KB tile
      int row = off >> 6;
      int col = (off & 63) >> 1;
      const u16* ga = A  + (size_t)(bm*128 + row) * 256 + k0 + col;
      const u16* gb = Bt + (size_t)(bn*128 + row) * 256 + k0 + col;
      __builtin_amdgcn_global_load_lds(
        (const __attribute__((address_space(1))) u32*)ga,
        (__attribute__((address_space(3))) u32*)((char*)As + off), 16, 0, 0);
      __builtin_amdgcn_global_load_lds(
        (const __attribute__((address_space(1))) u32*)gb,
        (__attribute__((address_space(3))) u32*)((char*)Bs + off), 16, 0, 0);
    }
    __syncthreads();
    bf16x8 af[4], bfr[4];
    #pragma unroll
    for (int t4 = 0; t4 < 4; ++t4) {
      af[t4]  = *(const bf16x8*)&As[(wm + t4*16 + (lane & 15)) * 32 + (lane >> 4) * 8];
      bfr[t4] = *(const bf16x8*)&Bs[(wn + t4*16 + (lane & 15)) * 32 + (lane >> 4) * 8];
    }
    #pragma unroll
    for (int mt = 0; mt < 4; ++mt)
      #pragma unroll
      for (int nt = 0; nt < 4; ++nt)
        acc[mt][nt] = __builtin_amdgcn_mfma_f32_16x16x32_bf16(af[mt], bfr[nt], acc[mt][nt], 0, 0, 0);
    __syncthreads();
  }
  const int cr = (lane >> 4) * 4;   // C/D: row = quad*4+reg, col = lane&15 (verified)
  const int cc = lane & 15;
  if (bn < 2) {
    // k half: row-major scalar stores (r1-proven pattern), kg stride 256
    #pragma unroll
    for (int mt = 0; mt < 4; ++mt)
      #pragma unroll
      for (int nt = 0; nt < 4; ++nt)
        #pragma unroll
        for (int r = 0; r < 4; ++r) {
          size_t row = (size_t)(bm*128 + wm + mt*16 + cr + r);
          int col = bn*128 + wn + nt*16 + cc;
          kg[row * 256 + col] = f2bf(acc[mt][nt][r]);
        }
  } else {
    // v half: stage transposed tile tr[c][r] (c = v-dim local, r = n local), pad 136
    #pragma unroll
    for (int mt = 0; mt < 4; ++mt)
      #pragma unroll
      for (int nt = 0; nt < 4; ++nt) {
        int c  = wn + nt*16 + cc;
        int r0 = wm + mt*16 + cr;
        u32* p = (u32*)&smem[c*136 + r0];
        p[0] = pack2(acc[mt][nt][0], acc[mt][nt][1]);
        p[1] = pack2(acc[mt][nt][2], acc[mt][nt][3]);
      }
    __syncthreads();
    int c = tid >> 1, half = tid & 1;
    int d = (bn - 2) * 128 + c;
    const u16* srcp = &smem[c*136 + half*64];
    u16* dstp = vtg + (size_t)(bm >> 5)*1048576 + (size_t)d*4096 + (bm & 31)*128 + half*64;
    #pragma unroll
    for (int i = 0; i < 8; ++i)
      *(uint4*)(dstp + i*8) = *(const uint4*)(srcp + i*8);
  }
}

// ---------------- K4: q = LN(slots)@Wq^T -> bf16 ----------------
__global__ __launch_bounds__(256) void q_kernel(
    const float* __restrict__ slots, const float* __restrict__ gw, const float* __restrict__ bw,
    const float* __restrict__ WqT, u16* __restrict__ qbf)
{
  __shared__ float ln[2][256];
  int t = threadIdx.x, wv = t >> 6, lane = t & 63;
  int base = blockIdx.x * 2;
  if (wv < 2) {
    int row = base + wv;
    float4 xv = *(const float4*)(slots + (size_t)row*256 + lane*4);
    float s  = xv.x + xv.y + xv.z + xv.w;
    float sq = xv.x*xv.x + xv.y*xv.y + xv.z*xv.z + xv.w*xv.w;
    #pragma unroll
    for (int m = 32; m >= 1; m >>= 1) { s += __shfl_xor(s, m, 64); sq += __shfl_xor(sq, m, 64); }
    float mean = s * (1.f/256.f);
    float rstd = rsqrtf(sq * (1.f/256.f) - mean*mean + 1e-5f);
    float4 gv = *(const float4*)(gw + lane*4);
    float4 bv = *(const float4*)(bw + lane*4);
    ln[wv][lane*4+0] = (xv.x - mean)*rstd*gv.x + bv.x;
    ln[wv][lane*4+1] = (xv.y - mean)*rstd*gv.y + bv.y;
    ln[wv][lane*4+2] = (xv.z - mean)*rstd*gv.z + bv.z;
    ln[wv][lane*4+3] = (xv.w - mean)*rstd*gv.w + bv.w;
  }
  __syncthreads();
  float a0 = 0.f, a1 = 0.f;
  for (int d = 0; d < 256; ++d) {
    float w = WqT[d*256 + t];
    a0 += ln[0][d] * w;
    a1 += ln[1][d] * w;
  }
  qbf[(size_t)base*256 + t]     = f2bf(a0);
  qbf[(size_t)(base+1)*256 + t] = f2bf(a1);
}

// ---------------- K5: attn v5 — staged k-tile, reg-prefetched vT, 2 barriers ----------------
// grid (64 b, 64 cg); 64 n per block. LDS: k-tile 32KB (XOR-swizzled) + attnT 2.3KB.
__global__ __launch_bounds__(256) void attn_kernel(
    const u16* __restrict__ kg, const u16* __restrict__ vtg, const u16* __restrict__ qbf,
    float* __restrict__ updp, float* __restrict__ sums_p)
{
  __shared__ u16 tile[16384];      // k [64][256] bf16, chunk-swizzled
  __shared__ u16 attnT[16*72];     // [slot][n] bf16 (rows 8..15 unused)
  __shared__ float sums_w[4][8];
  const int b = blockIdx.x, cg = blockIdx.y;
  const int t = threadIdx.x, w = t >> 6, lane = t & 63;
  const int L15 = lane & 15, q4 = lane >> 4;
  const int n0 = cg*64;
  const int slot = L15 & 7;

  // ---- early prefetch: vT B-frags (consumed in PV, latency hidden) ----
  bf16x8 vb[2][4];
  #pragma unroll
  for (int ks = 0; ks < 2; ++ks)
    #pragma unroll
    for (int dt = 0; dt < 4; ++dt) {
      int d = (dt*4 + w)*16 + L15;
      vb[ks][dt] = *(const bf16x8*)(vtg + (size_t)b*1048576 + (size_t)d*4096 + n0 + ks*32 + q4*8);
    }
  // ---- q B-frags ----
  bf16x8 qf[8];
  {
    const u16* qp = qbf + ((size_t)b*8 + slot)*256;
    #pragma unroll
    for (int ks = 0; ks < 8; ++ks)
      qf[ks] = *(const bf16x8*)(qp + ks*32 + q4*8);
  }
  // ---- stage k-tile via global_load_lds (swizzled source) ----
  {
    const u16* srcbase = kg + (size_t)(b*4096 + n0)*256;
    #pragma unroll
    for (int j = 0; j < 8; ++j) {
      int i = w*8 + j;
      int n = i*2 + (lane >> 5);
      int p = lane & 31;
      int c = (p & 24) | ((p ^ n) & 7);
      const u16* src = srcbase + (size_t)n*256 + c*8;
      __builtin_amdgcn_global_load_lds(
        (const __attribute__((address_space(1))) u32*)src,
        (__attribute__((address_space(3))) u32*)((char*)tile + i*1024 + lane*16), 16, 0, 0);
    }
  }
  __syncthreads();   // barrier 1: k-tile ready (also drains vb/qf)

  // ---- logits: wave w does n-rows w*16..w*16+15 ----
  f32x4 lg = {};
  {
    int n = w*16 + L15;
    #pragma unroll
    for (int ks = 0; ks < 8; ++ks) {
      int cck = ks*4 + q4;
      int p = (cck & 24) | ((cck ^ n) & 7);
      bf16x8 af = *(const bf16x8*)&tile[n*256 + p*8];
      lg = __builtin_amdgcn_mfma_f32_16x16x32_bf16(af, qf[ks], lg, 0, 0, 0);
    }
  }
  // ---- softmax over slots (r3-verified) + attnT + col sums ----
  float av[4], tot = 0.f;
  #pragma unroll
  for (int r = 0; r < 4; ++r) {
    float val = lg[r];
    float mx = val;
    mx = fmaxf(mx, __shfl_xor(mx, 1, 64));
    mx = fmaxf(mx, __shfl_xor(mx, 2, 64));
    mx = fmaxf(mx, __shfl_xor(mx, 4, 64));
    float e = expf(val - mx);
    float se = e;
    se += __shfl_xor(se, 1, 64);
    se += __shfl_xor(se, 2, 64);
    se += __shfl_xor(se, 4, 64);
    av[r] = e / se + EPSA;
    tot += av[r];
  }
  if (L15 < 8) {
    u32* p = (u32*)&attnT[L15*72 + w*16 + q4*4];
    p[0] = pack2(av[0], av[1]);
    p[1] = pack2(av[2], av[3]);
  }
  tot += __shfl_xor(tot, 16, 64);
  tot += __shfl_xor(tot, 32, 64);
  if (q4 == 0 && L15 < 8) sums_w[w][L15] = tot;
  __syncthreads();   // barrier 2: attnT + sums ready

  // ---- PV: A = attnT (LDS), B = vb (regs) ----
  f32x4 accp[4] = {};
  #pragma unroll
  for (int ks = 0; ks < 2; ++ks) {
    bf16x8 pa = *(const bf16x8*)&attnT[slot*72 + ks*32 + q4*8];
    #pragma unroll
    for (int dt = 0; dt < 4; ++dt)
      accp[dt] = __builtin_amdgcn_mfma_f32_16x16x32_bf16(pa, vb[ks][dt], accp[dt], 0, 0, 0);
  }
  // ---- store partials (rows 0..7 = slots, via q4<2) ----
  if (q4 < 2) {
    float* up = updp + ((size_t)(b*NCG + cg))*2048;
    #pragma unroll
    for (int dt = 0; dt < 4; ++dt) {
      int d = (dt*4 + w)*16 + L15;
      #pragma unroll
      for (int r = 0; r < 4; ++r)
        up[(q4*4 + r)*256 + d] = accp[dt][r];
    }
  }
  if (t < 8)
    sums_p[(b*NCG + cg)*8 + t] = sums_w[0][t] + sums_w[1][t] + sums_w[2][t] + sums_w[3][t];
}

// ---------------- K6: partial-reduce + GRU + (optional) MLP ----------------
__global__ __launch_bounds__(256) void grumlp_kernel(
    const float* __restrict__ updp, const float* __restrict__ sums_p,
    const float* __restrict__ WihT, const float* __restrict__ WhhT,
    const float* __restrict__ bih, const float* __restrict__ bhh,
    const float* __restrict__ gm, const float* __restrict__ bm,
    const float* __restrict__ W1T, const float* __restrict__ b1,
    const float* __restrict__ W2T, const float* __restrict__ b2,
    float* __restrict__ slots, int do_mlp)
{
  __shared__ float xs[4][256], hs[4][256];
  __shared__ float ln[4][256];
  __shared__ float hb[4][512];
  int t = threadIdx.x, w = t >> 6, lane = t & 63;
  int base = blockIdx.x * 4;
  #pragma unroll
  for (int g = 0; g < 4; ++g) {
    int row = base + g;
    int b = row >> 3, s = row & 7;
    float u = 0.f, sm = 0.f;
    for (int c = 0; c < NCG; ++c) {
      u  += updp[((size_t)(b*NCG + c)*8 + s)*256 + t];
      sm += sums_p[(b*NCG + c)*8 + s];
    }
    xs[g][t] = u / sm;
    hs[g][t] = slots[(size_t)row*256 + t];
  }
  __syncthreads();
  float ra[4] = {}, za[4] = {}, ia[4] = {}, ha[4] = {};
  for (int d = 0; d < 256; ++d) {
    float wir = WihT[d*768 + t], wiz = WihT[d*768 + 256 + t], win = WihT[d*768 + 512 + t];
    float whr = WhhT[d*768 + t], whz = WhhT[d*768 + 256 + t], whn = WhhT[d*768 + 512 + t];
    #pragma unroll
    for (int g = 0; g < 4; ++g) {
      float xx = xs[g][d], hh = hs[g][d];
      ra[g] += xx*wir + hh*whr;
      za[g] += xx*wiz + hh*whz;
      ia[g] += xx*win;
      ha[g] += hh*whn;
    }
  }
  float bir = bih[t], biz = bih[256+t], bin = bih[512+t];
  float bhr = bhh[t], bhz = bhh[256+t], bhn = bhh[512+t];
  float nv[4];
  #pragma unroll
  for (int g = 0; g < 4; ++g) {
    float r  = 1.f/(1.f + expf(-(ra[g] + bir + bhr)));
    float z  = 1.f/(1.f + expf(-(za[g] + biz + bhz)));
    float nn = tanhf(ia[g] + bin + r*(ha[g] + bhn));
    nv[g] = (1.f - z)*nn + z*hs[g][t];
  }
  if (!do_mlp) {
    #pragma unroll
    for (int g = 0; g < 4; ++g)
      slots[(size_t)(base+g)*256 + t] = nv[g];
    return;
  }
  #pragma unroll
  for (int g = 0; g < 4; ++g) xs[g][t] = nv[g];
  __syncthreads();
  {
    float4 xv = *(const float4*)&xs[w][lane*4];
    float s  = xv.x + xv.y + xv.z + xv.w;
    float sq = xv.x*xv.x + xv.y*xv.y + xv.z*xv.z + xv.w*xv.w;
    #pragma unroll
    for (int m = 32; m >= 1; m >>= 1) { s += __shfl_xor(s, m, 64); sq += __shfl_xor(sq, m, 64); }
    float mean = s * (1.f/256.f);
    float rstd = rsqrtf(sq * (1.f/256.f) - mean*mean + 1e-5f);
    float4 gv = *(const float4*)(gm + lane*4);
    float4 bv = *(const float4*)(bm + lane*4);
    ln[w][lane*4+0] = (xv.x - mean)*rstd*gv.x + bv.x;
    ln[w][lane*4+1] = (xv.y - mean)*rstd*gv.y + bv.y;
    ln[w][lane*4+2] = (xv.z - mean)*rstd*gv.z + bv.z;
    ln[w][lane*4+3] = (xv.w - mean)*rstd*gv.w + bv.w;
  }
  __syncthreads();
  float h0[4] = {}, h1[4] = {};
  for (int d = 0; d < 256; ++d) {
    float w0 = W1T[d*512 + t], w1 = W1T[d*512 + 256 + t];
    #pragma unroll
    for (int g = 0; g < 4; ++g) { float l = ln[g][d]; h0[g] += l*w0; h1[g] += l*w1; }
  }
  float bb0 = b1[t], bb1 = b1[256 + t];
  #pragma unroll
  for (int g = 0; g < 4; ++g) {
    hb[g][t]       = fmaxf(h0[g] + bb0, 0.f);
    hb[g][256 + t] = fmaxf(h1[g] + bb1, 0.f);
  }
  __syncthreads();
  float o[4] = {};
  for (int hh = 0; hh < 512; ++hh) {
    float ww = W2T[hh*256 + t];
    #pragma unroll
    for (int g = 0; g < 4; ++g) o[g] += hb[g][hh] * ww;
  }
  float b2v = b2[t];
  #pragma unroll
  for (int g = 0; g < 4; ++g)
    slots[(size_t)(base+g)*256 + t] = xs[g][t] + o[g] + b2v;
}

// ---------------- host ----------------
extern "C" void kernel_launch(void* const* d_in, const int* in_sizes, int n_in,
                              void* d_out, int out_size, void* d_ws, size_t ws_size,
                              hipStream_t stream)
{
  (void)in_sizes; (void)n_in; (void)out_size; (void)ws_size;
  const float* inputs = (const float*)d_in[0];
  const float* noise  = (const float*)d_in[1];
  const float* mu     = (const float*)d_in[2];
  const float* lsig   = (const float*)d_in[3];
  const float* g_in   = (const float*)d_in[4];
  const float* b_in   = (const float*)d_in[5];
  const float* g_sl   = (const float*)d_in[6];
  const float* b_sl   = (const float*)d_in[7];
  const float* g_mlp  = (const float*)d_in[8];
  const float* b_mlp  = (const float*)d_in[9];
  const float* Wq     = (const float*)d_in[10];
  const float* Wk     = (const float*)d_in[11];
  const float* Wv     = (const float*)d_in[12];
  const float* Wih    = (const float*)d_in[13];
  const float* Whh    = (const float*)d_in[14];
  const float* bih    = (const float*)d_in[15];
  const float* bhh    = (const float*)d_in[16];
  const float* W1     = (const float*)d_in[17];
  const float* b1     = (const float*)d_in[18];
  const float* W2     = (const float*)d_in[19];
  const float* b2     = (const float*)d_in[20];

  char* ws = (char*)d_ws;
  u16*   x_bf   = (u16*)  (ws + OFF_XBF);
  u16*   kg     = (u16*)  (ws + OFF_KG);
  u16*   vtg    = (u16*)  (ws + OFF_VTG);
  float* slots  = (float*)(ws + OFF_SLOTS);
  u16*   qb     = (u16*)  (ws + OFF_QBF);
  float* updp   = (float*)(ws + OFF_UPDP);
  float* sums_p = (float*)(ws + OFF_SUMSP);
  u16*   Wc     = (u16*)  (ws + OFF_WC);
  float* WqT    = (float*)(ws + OFF_WQT);
  float* WihT   = (float*)(ws + OFF_WIHT);
  float* WhhT   = (float*)(ws + OFF_WHHT);
  float* W1T    = (float*)(ws + OFF_W1T);
  float* W2T    = (float*)(ws + OFF_W2T);

  prep_kernel<<<768, 256, 0, stream>>>(Wq, Wk, Wv, Wih, Whh, W1, W2,
                                       Wc, WqT, WihT, WhhT, W1T, W2T);
  slots_init_kernel<<<512, 256, 0, stream>>>(noise, mu, lsig, slots);
  ln_cast_kernel<<<NROW/4, 256, 0, stream>>>(inputs, g_in, b_in, x_bf);
  gemm_kv_kernel<<<dim3(NROW/128, 4), 256, 0, stream>>>(x_bf, Wc, kg, vtg);

  for (int it = 0; it < 3; ++it) {
    q_kernel<<<NSLOT/2, 256, 0, stream>>>(slots, g_sl, b_sl, WqT, qb);
    attn_kernel<<<dim3(NB, NCG), 256, 0, stream>>>(kg, vtg, qb, updp, sums_p);
    grumlp_kernel<<<NSLOT/4, 256, 0, stream>>>(updp, sums_p, WihT, WhhT, bih, bhh,
                                               g_mlp, b_mlp, W1T, b1, W2T, b2,
                                               slots, (it < 2) ? 1 : 0);
  }
  hipMemcpyAsync(d_out, slots, (size_t)NSLOT*NS*sizeof(float),
                 hipMemcpyDeviceToDevice, stream);
}

// Round 5
// 1016.621 us; speedup vs baseline: 1.1122x; 1.1122x over previous
//
#include <hip/hip_runtime.h>
#include <math.h>

#define NB 64
#define NN 4096
#define ND 256
#define NS 256
#define NK 8
#define NH 512
#define NROW (NB*NN)
#define NSLOT (NB*NK)
#define EPSA 1e-8f
#define NCG 16            // n-chunks per batch in attn (256 n each)

typedef unsigned short u16;
typedef unsigned int   u32;
typedef __bf16 bf16x8 __attribute__((ext_vector_type(8)));
typedef float  f32x4  __attribute__((ext_vector_type(4)));

__device__ __forceinline__ u16 f2bf(float f) {
  union { float f; u32 i; } v; v.f = f;
  u32 x = v.i;
  return (u16)((x + 0x7FFFu + ((x >> 16) & 1u)) >> 16);
}
__device__ __forceinline__ u32 pack2(float a, float b) {
  return (u32)f2bf(a) | ((u32)f2bf(b) << 16);
}

// ---------------- workspace layout (bytes) ----------------
// kpre: A-frag layout. tile = (global_n>>4)*8 + ks ; halfword offset in tile =
//       (n&15)*32 + ((d>>3)&3)*8 + (d&7)          [d = k-dim 0..255]
// vpre: B-frag layout, per batch b. tile = (d>>4)*128 + (nn>>5) ; offset =
//       (d&15)*32 + ((nn>>3)&3)*8 + (nn&7)        [d = v-dim 0..255]
#define OFF_XBF    0ULL            // 134217728
#define OFF_KPRE   134217728ULL    // 134217728
#define OFF_VPRE   268435456ULL    // 134217728
#define OFF_SLOTS  402653184ULL    // 524288
#define OFF_QBF    403177472ULL    // 262144
#define OFF_UPDP   403439616ULL    // 64*16*8*256 f32 = 8388608
#define OFF_SUMSP  411828224ULL    // 64*16*8 f32 = 32768
#define OFF_WC     411860992ULL    // 262144
#define OFF_WQT    412123136ULL    // 262144
#define OFF_WIHT   412385280ULL    // 786432
#define OFF_WHHT   413171712ULL    // 786432
#define OFF_W1T    413958144ULL    // 524288
#define OFF_W2T    414482432ULL    // 524288  (end ~396 MB)

// ---------------- K0: weight prep (proven) ----------------
__global__ __launch_bounds__(256) void prep_kernel(
    const float* __restrict__ Wq, const float* __restrict__ Wk, const float* __restrict__ Wv,
    const float* __restrict__ Wih, const float* __restrict__ Whh,
    const float* __restrict__ W1, const float* __restrict__ W2,
    u16* __restrict__ Wc, float* __restrict__ WqT, float* __restrict__ WihT,
    float* __restrict__ WhhT, float* __restrict__ W1T, float* __restrict__ W2T)
{
  int idx = blockIdx.x * 256 + threadIdx.x;   // 768*256
  if (idx < 512*256) {
    int j = idx >> 8, d = idx & 255;
    float w = (j < 256) ? Wk[idx] * 0.0625f : Wv[idx - 65536];
    Wc[idx] = f2bf(w);
    W1T[d*512 + j] = W1[idx];
  }
  if (idx < 256*256) {
    int j = idx >> 8, d = idx & 255;
    WqT[d*256 + j] = Wq[idx];
  }
  if (idx < 768*256) {
    int j = idx >> 8, d = idx & 255;
    WihT[d*768 + j] = Wih[idx];
    WhhT[d*768 + j] = Whh[idx];
  }
  if (idx < 256*512) {
    int j = idx >> 9, h = idx & 511;
    W2T[h*256 + j] = W2[idx];
  }
}

// ---------------- K1: slots init ----------------
__global__ __launch_bounds__(256) void slots_init_kernel(
    const float* __restrict__ noise, const float* __restrict__ mu,
    const float* __restrict__ lsig, float* __restrict__ slots)
{
  int idx = blockIdx.x * 256 + threadIdx.x;
  int s = idx & 255;
  slots[idx] = mu[s] + expf(lsig[s]) * noise[idx];
}

// ---------------- K2: LayerNorm(inputs) -> bf16 (r1 proven) ----------------
__global__ __launch_bounds__(256) void ln_cast_kernel(
    const float* __restrict__ x, const float* __restrict__ g, const float* __restrict__ bb,
    u16* __restrict__ out)
{
  int row = blockIdx.x * 4 + (threadIdx.x >> 6);
  int lane = threadIdx.x & 63;
  float4 xv = *(const float4*)(x + (size_t)row * 256 + lane * 4);
  float s  = xv.x + xv.y + xv.z + xv.w;
  float sq = xv.x*xv.x + xv.y*xv.y + xv.z*xv.z + xv.w*xv.w;
  #pragma unroll
  for (int m = 32; m >= 1; m >>= 1) { s += __shfl_xor(s, m, 64); sq += __shfl_xor(sq, m, 64); }
  float mean = s * (1.f/256.f);
  float rstd = rsqrtf(sq * (1.f/256.f) - mean*mean + 1e-5f);
  float4 gv = *(const float4*)(g + lane*4);
  float4 bv = *(const float4*)(bb + lane*4);
  ushort4 o;
  o.x = f2bf((xv.x - mean) * rstd * gv.x + bv.x);
  o.y = f2bf((xv.y - mean) * rstd * gv.y + bv.y);
  o.z = f2bf((xv.z - mean) * rstd * gv.z + bv.z);
  o.w = f2bf((xv.w - mean) * rstd * gv.w + bv.w);
  *(ushort4*)(out + (size_t)row * 256 + lane*4) = o;
}

// ---------------- K3: kv GEMM (r1 core) -> kpre / vpre frag layouts ----------------
// grid 8192 linear; bn = idx&3 (fastest -> A-tile L2/L3 reuse), bm = idx>>2.
__global__ __launch_bounds__(256) void gemm_kv_kernel(
    const u16* __restrict__ A, const u16* __restrict__ Bt,
    u16* __restrict__ kpre, u16* __restrict__ vpre)
{
  __shared__ u16 As[4096];
  __shared__ u16 Bs[4096];
  const int tid = threadIdx.x;
  const int lane = tid & 63;
  const int wv = tid >> 6;
  const int bm = blockIdx.x >> 2;
  const int bn = blockIdx.x & 3;
  const int wm = (wv & 1) * 64;
  const int wn = (wv >> 1) * 64;

  f32x4 acc[4][4] = {};

  for (int k0 = 0; k0 < 256; k0 += 32) {
    #pragma unroll
    for (int r = 0; r < 2; ++r) {
      int off = ((r*4 + wv) << 10) + lane*16;   // byte offset into 8KB tile
      int row = off >> 6;
      int col = (off & 63) >> 1;
      const u16* ga = A  + (size_t)(bm*128 + row) * 256 + k0 + col;
      const u16* gb = Bt + (size_t)(bn*128 + row) * 256 + k0 + col;
      __builtin_amdgcn_global_load_lds(
        (const __attribute__((address_space(1))) u32*)ga,
        (__attribute__((address_space(3))) u32*)((char*)As + off), 16, 0, 0);
      __builtin_amdgcn_global_load_lds(
        (const __attribute__((address_space(1))) u32*)gb,
        (__attribute__((address_space(3))) u32*)((char*)Bs + off), 16, 0, 0);
    }
    __syncthreads();
    bf16x8 af[4], bfr[4];
    #pragma unroll
    for (int t4 = 0; t4 < 4; ++t4) {
      af[t4]  = *(const bf16x8*)&As[(wm + t4*16 + (lane & 15)) * 32 + (lane >> 4) * 8];
      bfr[t4] = *(const bf16x8*)&Bs[(wn + t4*16 + (lane & 15)) * 32 + (lane >> 4) * 8];
    }
    #pragma unroll
    for (int mt = 0; mt < 4; ++mt)
      #pragma unroll
      for (int nt = 0; nt < 4; ++nt)
        acc[mt][nt] = __builtin_amdgcn_mfma_f32_16x16x32_bf16(af[mt], bfr[nt], acc[mt][nt], 0, 0, 0);
    __syncthreads();
  }
  const int cr = (lane >> 4) * 4;   // C/D: row = quad*4+reg, col = lane&15 (verified)
  const int cc = lane & 15;
  if (bn < 2) {
    // k half -> kpre A-frag layout
    #pragma unroll
    for (int mt = 0; mt < 4; ++mt) {
      int ntile = bm*8 + (wm >> 4) + mt;
      #pragma unroll
      for (int nt = 0; nt < 4; ++nt) {
        int d = bn*128 + wn + nt*16 + cc;      // k-dim 0..255
        size_t base = ((size_t)ntile*8 + (d >> 5))*512 + ((d >> 3) & 3)*8 + (d & 7);
        #pragma unroll
        for (int r = 0; r < 4; ++r)
          kpre[base + (cr + r)*32] = f2bf(acc[mt][nt][r]);
      }
    }
  } else {
    // v half -> vpre B-frag layout
    #pragma unroll
    for (int mt = 0; mt < 4; ++mt) {
      #pragma unroll
      for (int nt = 0; nt < 4; ++nt) {
        int dv = (bn - 2)*128 + wn + nt*16 + cc;   // v-dim 0..255
        #pragma unroll
        for (int r = 0; r < 4; ++r) {
          int n = bm*128 + wm + mt*16 + cr + r;
          int b = n >> 12, nn = n & 4095;
          size_t addr = (size_t)b*1048576
                      + ((size_t)(dv >> 4)*128 + (nn >> 5))*512
                      + (dv & 15)*32 + ((nn >> 3) & 3)*8 + (nn & 7);
          vpre[addr] = f2bf(acc[mt][nt][r]);
        }
      }
    }
  }
}

// ---------------- K4: q = LN(slots)@Wq^T -> bf16 (initial q only) ----------------
__global__ __launch_bounds__(256) void q_kernel(
    const float* __restrict__ slots, const float* __restrict__ gw, const float* __restrict__ bw,
    const float* __restrict__ WqT, u16* __restrict__ qbf)
{
  __shared__ float ln[2][256];
  int t = threadIdx.x, wv = t >> 6, lane = t & 63;
  int base = blockIdx.x * 2;
  if (wv < 2) {
    int row = base + wv;
    float4 xv = *(const float4*)(slots + (size_t)row*256 + lane*4);
    float s  = xv.x + xv.y + xv.z + xv.w;
    float sq = xv.x*xv.x + xv.y*xv.y + xv.z*xv.z + xv.w*xv.w;
    #pragma unroll
    for (int m = 32; m >= 1; m >>= 1) { s += __shfl_xor(s, m, 64); sq += __shfl_xor(sq, m, 64); }
    float mean = s * (1.f/256.f);
    float rstd = rsqrtf(sq * (1.f/256.f) - mean*mean + 1e-5f);
    float4 gv = *(const float4*)(gw + lane*4);
    float4 bv = *(const float4*)(bw + lane*4);
    ln[wv][lane*4+0] = (xv.x - mean)*rstd*gv.x + bv.x;
    ln[wv][lane*4+1] = (xv.y - mean)*rstd*gv.y + bv.y;
    ln[wv][lane*4+2] = (xv.z - mean)*rstd*gv.z + bv.z;
    ln[wv][lane*4+3] = (xv.w - mean)*rstd*gv.w + bv.w;
  }
  __syncthreads();
  float a0 = 0.f, a1 = 0.f;
  for (int d = 0; d < 256; ++d) {
    float w = WqT[d*256 + t];
    a0 += ln[0][d] * w;
    a1 += ln[1][d] * w;
  }
  qbf[(size_t)base*256 + t]     = f2bf(a0);
  qbf[(size_t)(base+1)*256 + t] = f2bf(a1);
}

// ---------------- K5: attn v6 — frag-native streaming, 1 barrier ----------------
// grid (64 b, 16 cg); 256 n per block. Only attnT (4.2KB) in LDS.
__global__ __launch_bounds__(256) void attn_kernel(
    const u16* __restrict__ kpre, const u16* __restrict__ vpre, const u16* __restrict__ qbf,
    float* __restrict__ updp, float* __restrict__ sums_p)
{
  __shared__ u16 attnT[8*264];    // [slot][n], pad 264 (bank-spread)
  __shared__ float sums_w[4][8];
  const int b = blockIdx.x, cg = blockIdx.y;
  const int t = threadIdx.x, w = t >> 6, lane = t & 63;
  const int L15 = lane & 15, q4 = lane >> 4;
  const int slot = L15 & 7;

  // q B-frags
  bf16x8 qf[8];
  {
    const u16* qp = qbf + ((size_t)b*8 + slot)*256;
    #pragma unroll
    for (int ks = 0; ks < 8; ++ks)
      qf[ks] = *(const bf16x8*)(qp + ks*32 + q4*8);
  }

  // ---- logits + softmax: wave w covers n = w*64 .. w*64+63 (4 ntiles of 16) ----
  const u16* kbase = kpre + (size_t)(b*256 + cg*16)*8*512 + L15*32 + q4*8;
  float tot = 0.f;
  #pragma unroll
  for (int i = 0; i < 4; ++i) {
    f32x4 lg = {};
    const u16* ktile = kbase + (size_t)(w*4 + i)*8*512;
    #pragma unroll
    for (int ks = 0; ks < 8; ++ks) {
      bf16x8 af = *(const bf16x8*)(ktile + ks*512);
      lg = __builtin_amdgcn_mfma_f32_16x16x32_bf16(af, qf[ks], lg, 0, 0, 0);
    }
    float av[4];
    #pragma unroll
    for (int r = 0; r < 4; ++r) {
      float val = lg[r];
      float mx = val;
      mx = fmaxf(mx, __shfl_xor(mx, 1, 64));
      mx = fmaxf(mx, __shfl_xor(mx, 2, 64));
      mx = fmaxf(mx, __shfl_xor(mx, 4, 64));
      float e = expf(val - mx);
      float se = e;
      se += __shfl_xor(se, 1, 64);
      se += __shfl_xor(se, 2, 64);
      se += __shfl_xor(se, 4, 64);
      av[r] = e / se + EPSA;
      tot += av[r];
    }
    if (L15 < 8) {
      u32* p = (u32*)&attnT[slot*264 + (w*4 + i)*16 + q4*4];
      p[0] = pack2(av[0], av[1]);
      p[1] = pack2(av[2], av[3]);
    }
  }
  tot += __shfl_xor(tot, 16, 64);
  tot += __shfl_xor(tot, 32, 64);
  if (q4 == 0 && L15 < 8) sums_w[w][L15] = tot;
  __syncthreads();   // the ONE barrier

  // ---- PV: A = attnT (LDS), B = vpre frags (global, coalesced) ----
  f32x4 accp[4] = {};
  const u16* vbase = vpre + (size_t)b*1048576 + L15*32 + q4*8;
  #pragma unroll
  for (int ks2 = 0; ks2 < 8; ++ks2) {
    bf16x8 pa = *(const bf16x8*)&attnT[slot*264 + ks2*32 + q4*8];
    #pragma unroll
    for (int dt = 0; dt < 4; ++dt) {
      int dtile = w*4 + dt;
      bf16x8 vb = *(const bf16x8*)(vbase + (size_t)(dtile*128 + cg*8 + ks2)*512);
      accp[dt] = __builtin_amdgcn_mfma_f32_16x16x32_bf16(pa, vb, accp[dt], 0, 0, 0);
    }
  }
  if (q4 < 2) {
    float* up = updp + ((size_t)(b*NCG + cg))*2048;
    #pragma unroll
    for (int dt = 0; dt < 4; ++dt) {
      int d = (w*4 + dt)*16 + L15;
      #pragma unroll
      for (int r = 0; r < 4; ++r)
        up[(q4*4 + r)*256 + d] = accp[dt][r];
    }
  }
  if (t < 8)
    sums_p[(b*NCG + cg)*8 + t] = sums_w[0][t] + sums_w[1][t] + sums_w[2][t] + sums_w[3][t];
}

// ---------------- K6: reduce + GRU + MLP + next-iter q (fused) ----------------
// 256 blocks x 2 slot-rows.
__global__ __launch_bounds__(256) void grumlp_kernel(
    const float* __restrict__ updp, const float* __restrict__ sums_p,
    const float* __restrict__ WihT, const float* __restrict__ WhhT,
    const float* __restrict__ bih, const float* __restrict__ bhh,
    const float* __restrict__ gm, const float* __restrict__ bm,
    const float* __restrict__ W1T, const float* __restrict__ b1,
    const float* __restrict__ W2T, const float* __restrict__ b2,
    const float* __restrict__ gq, const float* __restrict__ bq,
    const float* __restrict__ WqT,
    float* __restrict__ slots, u16* __restrict__ qbf, int do_mlp)
{
  __shared__ float xs[2][256], hs[2][256];
  __shared__ float ln[2][256];
  __shared__ float hb[2][512];
  int t = threadIdx.x, w = t >> 6, lane = t & 63;
  int base = blockIdx.x * 2;
  #pragma unroll
  for (int g = 0; g < 2; ++g) {
    int row = base + g;
    int b = row >> 3, s = row & 7;
    float u = 0.f, sm = 0.f;
    #pragma unroll
    for (int c = 0; c < NCG; ++c) {
      u  += updp[((size_t)(b*NCG + c)*8 + s)*256 + t];
      sm += sums_p[(b*NCG + c)*8 + s];
    }
    xs[g][t] = u / sm;
    hs[g][t] = slots[(size_t)row*256 + t];
  }
  __syncthreads();
  float ra[2] = {}, za[2] = {}, ia[2] = {}, ha[2] = {};
  for (int d = 0; d < 256; ++d) {
    float wir = WihT[d*768 + t], wiz = WihT[d*768 + 256 + t], win = WihT[d*768 + 512 + t];
    float whr = WhhT[d*768 + t], whz = WhhT[d*768 + 256 + t], whn = WhhT[d*768 + 512 + t];
    #pragma unroll
    for (int g = 0; g < 2; ++g) {
      float xx = xs[g][d], hh = hs[g][d];
      ra[g] += xx*wir + hh*whr;
      za[g] += xx*wiz + hh*whz;
      ia[g] += xx*win;
      ha[g] += hh*whn;
    }
  }
  float bir = bih[t], biz = bih[256+t], bin = bih[512+t];
  float bhr = bhh[t], bhz = bhh[256+t], bhn = bhh[512+t];
  float nv[2];
  #pragma unroll
  for (int g = 0; g < 2; ++g) {
    float r  = 1.f/(1.f + expf(-(ra[g] + bir + bhr)));
    float z  = 1.f/(1.f + expf(-(za[g] + biz + bhz)));
    float nn = tanhf(ia[g] + bin + r*(ha[g] + bhn));
    nv[g] = (1.f - z)*nn + z*hs[g][t];
  }
  if (!do_mlp) {
    #pragma unroll
    for (int g = 0; g < 2; ++g)
      slots[(size_t)(base+g)*256 + t] = nv[g];
    return;
  }
  #pragma unroll
  for (int g = 0; g < 2; ++g) xs[g][t] = nv[g];
  __syncthreads();
  // LN (g_mlp) — waves 0,1 own rows 0,1
  if (w < 2) {
    float4 xv = *(const float4*)&xs[w][lane*4];
    float s  = xv.x + xv.y + xv.z + xv.w;
    float sq = xv.x*xv.x + xv.y*xv.y + xv.z*xv.z + xv.w*xv.w;
    #pragma unroll
    for (int m = 32; m >= 1; m >>= 1) { s += __shfl_xor(s, m, 64); sq += __shfl_xor(sq, m, 64); }
    float mean = s * (1.f/256.f);
    float rstd = rsqrtf(sq * (1.f/256.f) - mean*mean + 1e-5f);
    float4 gv = *(const float4*)(gm + lane*4);
    float4 bv = *(const float4*)(bm + lane*4);
    ln[w][lane*4+0] = (xv.x - mean)*rstd*gv.x + bv.x;
    ln[w][lane*4+1] = (xv.y - mean)*rstd*gv.y + bv.y;
    ln[w][lane*4+2] = (xv.z - mean)*rstd*gv.z + bv.z;
    ln[w][lane*4+3] = (xv.w - mean)*rstd*gv.w + bv.w;
  }
  __syncthreads();
  float h0[2] = {}, h1[2] = {};
  for (int d = 0; d < 256; ++d) {
    float w0 = W1T[d*512 + t], w1 = W1T[d*512 + 256 + t];
    #pragma unroll
    for (int g = 0; g < 2; ++g) { float l = ln[g][d]; h0[g] += l*w0; h1[g] += l*w1; }
  }
  float bb0 = b1[t], bb1 = b1[256 + t];
  #pragma unroll
  for (int g = 0; g < 2; ++g) {
    hb[g][t]       = fmaxf(h0[g] + bb0, 0.f);
    hb[g][256 + t] = fmaxf(h1[g] + bb1, 0.f);
  }
  __syncthreads();
  float o[2] = {};
  for (int hh = 0; hh < 512; ++hh) {
    float ww = W2T[hh*256 + t];
    #pragma unroll
    for (int g = 0; g < 2; ++g) o[g] += hb[g][hh] * ww;
  }
  float b2v = b2[t];
  #pragma unroll
  for (int g = 0; g < 2; ++g) {
    float snew = xs[g][t] + o[g] + b2v;
    slots[(size_t)(base+g)*256 + t] = snew;
    xs[g][t] = snew;
  }
  __syncthreads();
  // LN (g_sl) for next-iter q — waves 0,1 own rows 0,1
  if (w < 2) {
    float4 xv = *(const float4*)&xs[w][lane*4];
    float s  = xv.x + xv.y + xv.z + xv.w;
    float sq = xv.x*xv.x + xv.y*xv.y + xv.z*xv.z + xv.w*xv.w;
    #pragma unroll
    for (int m = 32; m >= 1; m >>= 1) { s += __shfl_xor(s, m, 64); sq += __shfl_xor(sq, m, 64); }
    float mean = s * (1.f/256.f);
    float rstd = rsqrtf(sq * (1.f/256.f) - mean*mean + 1e-5f);
    float4 gv = *(const float4*)(gq + lane*4);
    float4 bv = *(const float4*)(bq + lane*4);
    ln[w][lane*4+0] = (xv.x - mean)*rstd*gv.x + bv.x;
    ln[w][lane*4+1] = (xv.y - mean)*rstd*gv.y + bv.y;
    ln[w][lane*4+2] = (xv.z - mean)*rstd*gv.z + bv.z;
    ln[w][lane*4+3] = (xv.w - mean)*rstd*gv.w + bv.w;
  }
  __syncthreads();
  float a0 = 0.f, a1 = 0.f;
  for (int d = 0; d < 256; ++d) {
    float wq = WqT[d*256 + t];
    a0 += ln[0][d] * wq;
    a1 += ln[1][d] * wq;
  }
  qbf[(size_t)base*256 + t]     = f2bf(a0);
  qbf[(size_t)(base+1)*256 + t] = f2bf(a1);
}

// ---------------- host ----------------
extern "C" void kernel_launch(void* const* d_in, const int* in_sizes, int n_in,
                              void* d_out, int out_size, void* d_ws, size_t ws_size,
                              hipStream_t stream)
{
  (void)in_sizes; (void)n_in; (void)out_size; (void)ws_size;
  const float* inputs = (const float*)d_in[0];
  const float* noise  = (const float*)d_in[1];
  const float* mu     = (const float*)d_in[2];
  const float* lsig   = (const float*)d_in[3];
  const float* g_in   = (const float*)d_in[4];
  const float* b_in   = (const float*)d_in[5];
  const float* g_sl   = (const float*)d_in[6];
  const float* b_sl   = (const float*)d_in[7];
  const float* g_mlp  = (const float*)d_in[8];
  const float* b_mlp  = (const float*)d_in[9];
  const float* Wq     = (const float*)d_in[10];
  const float* Wk     = (const float*)d_in[11];
  const float* Wv     = (const float*)d_in[12];
  const float* Wih    = (const float*)d_in[13];
  const float* Whh    = (const float*)d_in[14];
  const float* bih    = (const float*)d_in[15];
  const float* bhh    = (const float*)d_in[16];
  const float* W1     = (const float*)d_in[17];
  const float* b1     = (const float*)d_in[18];
  const float* W2     = (const float*)d_in[19];
  const float* b2     = (const float*)d_in[20];

  char* ws = (char*)d_ws;
  u16*   x_bf   = (u16*)  (ws + OFF_XBF);
  u16*   kpre   = (u16*)  (ws + OFF_KPRE);
  u16*   vpre   = (u16*)  (ws + OFF_VPRE);
  float* slots  = (float*)(ws + OFF_SLOTS);
  u16*   qb     = (u16*)  (ws + OFF_QBF);
  float* updp   = (float*)(ws + OFF_UPDP);
  float* sums_p = (float*)(ws + OFF_SUMSP);
  u16*   Wc     = (u16*)  (ws + OFF_WC);
  float* WqT    = (float*)(ws + OFF_WQT);
  float* WihT   = (float*)(ws + OFF_WIHT);
  float* WhhT   = (float*)(ws + OFF_WHHT);
  float* W1T    = (float*)(ws + OFF_W1T);
  float* W2T    = (float*)(ws + OFF_W2T);

  prep_kernel<<<768, 256, 0, stream>>>(Wq, Wk, Wv, Wih, Whh, W1, W2,
                                       Wc, WqT, WihT, WhhT, W1T, W2T);
  slots_init_kernel<<<512, 256, 0, stream>>>(noise, mu, lsig, slots);
  ln_cast_kernel<<<NROW/4, 256, 0, stream>>>(inputs, g_in, b_in, x_bf);
  gemm_kv_kernel<<<8192, 256, 0, stream>>>(x_bf, Wc, kpre, vpre);
  q_kernel<<<NSLOT/2, 256, 0, stream>>>(slots, g_sl, b_sl, WqT, qb);

  for (int it = 0; it < 3; ++it) {
    attn_kernel<<<dim3(NB, NCG), 256, 0, stream>>>(kpre, vpre, qb, updp, sums_p);
    grumlp_kernel<<<NSLOT/2, 256, 0, stream>>>(updp, sums_p, WihT, WhhT, bih, bhh,
                                               g_mlp, b_mlp, W1T, b1, W2T, b2,
                                               g_sl, b_sl, WqT,
                                               slots, qb, (it < 2) ? 1 : 0);
  }
  hipMemcpyAsync(d_out, slots, (size_t)NSLOT*NS*sizeof(float),
                 hipMemcpyDeviceToDevice, stream);
}